// Round 5
// baseline (319.165 us; speedup 1.0000x reference)
//
#include <hip/hip_runtime.h>
#include <hip/hip_bf16.h>
#include <stdint.h>

// B=8192, T=U=1024, K=2048. GEMM [8192,2048]x[2048,4096p], packed gate cols:
//   pcg = (c>>6)*256 + ((c>>4)&3)*64 + g*16 + (c&15)
// BK=64 K-tiles, half-tile = 16 KB = [128 rows][64 k] bf16 with baked swizzle:
//   byte(r,k) = (r*8 + ((k>>3) ^ (r&7)))*16 + (k&7)*2    (16B chunk XOR swizzle)
// m201-style 8-phase schedule, double-buffered 2x64KB LDS, counted vmcnt(6).

typedef float f32x4 __attribute__((ext_vector_type(4)));
typedef __bf16 bf16x8 __attribute__((ext_vector_type(8)));

static __device__ __forceinline__ void gll16(const void* g, void* l) {
  __builtin_amdgcn_global_load_lds(
      (const __attribute__((address_space(1))) void*)g,
      (__attribute__((address_space(3))) void*)l, 16, 0, 0);
}

static __device__ __forceinline__ unsigned short f2bf(float f) {
  union { __hip_bfloat16 h; unsigned short u; } v{__float2bfloat16(f)};
  return v.u;
}

// ---- pack A: concat(x,h) -> [rbB 0..31][kt 0..31][half][swizzled 16KB] ----
__global__ void pack_a(const float* __restrict__ x, const float* __restrict__ h,
                       char* __restrict__ Ap) {
  int row = blockIdx.x;            // 0..8191
  int c8  = threadIdx.x;           // 0..255 : 16B chunk (8 k)
  int kt  = c8 >> 3, q = c8 & 7;
  int gk  = c8 * 8;
  const float* src = (gk < 1024) ? (x + (size_t)row * 1024 + gk)
                                 : (h + (size_t)row * 1024 + (gk - 1024));
  float4 lo = *(const float4*)src;
  float4 hi = *(const float4*)(src + 4);
  __attribute__((aligned(16))) unsigned short o[8] = {
      f2bf(lo.x), f2bf(lo.y), f2bf(lo.z), f2bf(lo.w),
      f2bf(hi.x), f2bf(hi.y), f2bf(hi.z), f2bf(hi.w) };
  int rbB = row >> 8, half = (row >> 7) & 1, r = row & 127;
  size_t dst = (((size_t)rbB * 32 + kt) * 2 + half) * 16384
             + (size_t)(r * 8 + (q ^ (r & 7))) * 16;
  *(int4*)(Ap + dst) = *(const int4*)o;
}

// ---- pack W: -> [cb 0..15][kt 0..31][half][swizzled 16KB], pcg layout ----
__global__ void pack_w(const float* __restrict__ Wi, const float* __restrict__ Wf,
                       const float* __restrict__ Wg, const float* __restrict__ Wo,
                       char* __restrict__ Wp) {
  __shared__ float tile[64][65];
  int kt = blockIdx.x;       // 0..31
  int cb = blockIdx.y;       // 0..15
  int g  = blockIdx.z;       // 0..3
  const float* W = (g == 0) ? Wi : (g == 1) ? Wf : (g == 2) ? Wg : Wo;
  int t = threadIdx.x;       // 0..255
  {
    int k  = t >> 2;                 // 0..63
    int c8 = (t & 3) * 16;           // 0,16,32,48
    const float* s = W + (size_t)(kt * 64 + k) * 1024 + cb * 64 + c8;
#pragma unroll
    for (int j4 = 0; j4 < 4; ++j4) {
      float4 v = *(const float4*)(s + j4 * 4);
      tile[k][c8 + j4 * 4 + 0] = v.x; tile[k][c8 + j4 * 4 + 1] = v.y;
      tile[k][c8 + j4 * 4 + 2] = v.z; tile[k][c8 + j4 * 4 + 3] = v.w;
    }
  }
  __syncthreads();
  {
    int cl = t >> 2;                 // 0..63 (real col - cb*64)
    int kq = t & 3;
    int rloc = (cl >> 4) * 64 + g * 16 + (cl & 15);   // packed row 0..255
    int half = rloc >> 7, r = rloc & 127;
#pragma unroll
    for (int p = 0; p < 2; ++p) {
      int q = kq + p * 4;            // 0..7
      __attribute__((aligned(16))) unsigned short o[8];
#pragma unroll
      for (int j = 0; j < 8; ++j) o[j] = f2bf(tile[q * 8 + j][cl]);
      size_t dst = (((size_t)cb * 32 + kt) * 2 + half) * 16384
                 + (size_t)(r * 8 + (q ^ (r & 7))) * 16;
      *(int4*)(Wp + dst) = *(const int4*)o;
    }
  }
}

// ---- 256x256 GEMM, 8 waves (2M x 4N), BK=64, 8-phase schedule ----
__global__ __launch_bounds__(512, 2)
void lstm_gemm(const char* __restrict__ Ap, const char* __restrict__ Wp,
               const float* __restrict__ c_in,
               const float* __restrict__ b_i, const float* __restrict__ b_f,
               const float* __restrict__ b_g, const float* __restrict__ b_o,
               float* __restrict__ out) {
  __shared__ __align__(128) char smem[131072];  // 2 bufs x [A0|A1|B0|B1] 16KB

  int tid = threadIdx.x;
  int w = tid >> 6, lane = tid & 63, l15 = lane & 15, lq = lane >> 4;
  int wm = w >> 2, wc = w & 3;

  int bid = blockIdx.x;
  int wg = (bid & 7) * 64 + (bid >> 3);   // 512 % 8 == 0 -> bijective
  int rbB = wg >> 4, cb = wg & 15;

  const char* aT = Ap + (size_t)rbB * (32 * 2 * 16384);
  const char* bT = Wp + (size_t)cb  * (32 * 2 * 16384);

  f32x4 acc[8][4] = {};

  // LDS read offsets (within one 64KB buffer)
  unsigned aOff[8][2], bOff[4][2];
#pragma unroll
  for (int mf = 0; mf < 8; ++mf) {
    int r = mf * 16 + l15;     // local row within wave's A-half
#pragma unroll
    for (int ks = 0; ks < 2; ++ks) {
      int q = ks * 4 + lq;
      aOff[mf][ks] = (unsigned)(wm * 16384 + (r * 8 + (q ^ (r & 7))) * 16);
    }
  }
#pragma unroll
  for (int nf = 0; nf < 4; ++nf) {
    int r = (wc & 1) * 64 + nf * 16 + l15;  // local row within B-half
#pragma unroll
    for (int ks = 0; ks < 2; ++ks) {
      int q = ks * 4 + lq;
      bOff[nf][ks] = (unsigned)(32768 + (wc >> 1) * 16384 + (r * 8 + (q ^ (r & 7))) * 16);
    }
  }

  auto stA = [&](int kt, int h) {
    size_t s = (((size_t)(kt & 31)) * 2 + h) * 16384 + (size_t)tid * 16;
    char* d = smem + (kt & 1) * 65536 + h * 16384 + tid * 16;
    gll16(aT + s, d); gll16(aT + s + 8192, d + 8192);
  };
  auto stB = [&](int kt, int h) {
    size_t s = (((size_t)(kt & 31)) * 2 + h) * 16384 + (size_t)tid * 16;
    char* d = smem + (kt & 1) * 65536 + 32768 + h * 16384 + tid * 16;
    gll16(bT + s, d); gll16(bT + s + 8192, d + 8192);
  };

#define BAR __builtin_amdgcn_s_barrier()
#define PRIO1 __builtin_amdgcn_s_setprio(1)
#define PRIO0 __builtin_amdgcn_s_setprio(0)
#define VM6 asm volatile("s_waitcnt vmcnt(6)" ::: "memory")

  // prologue: kt0 all 4 halves (8 loads), kt1 B0,A0,B1 (6 loads)
  stA(0, 0); stA(0, 1); stB(0, 0); stB(0, 1);
  stB(1, 0); stA(1, 0); stB(1, 1);
  VM6;
  BAR;

  bf16x8 aF[4][2], bN0[2][2], bN2[2][2];

  auto LDA = [&](const char* s, int mb) {
#pragma unroll
    for (int m = 0; m < 4; ++m)
#pragma unroll
      for (int ks = 0; ks < 2; ++ks)
        aF[m][ks] = *(const bf16x8*)(s + aOff[mb + m][ks]);
  };
  auto LDB = [&](const char* s, bf16x8 (&b)[2][2], int nb) {
#pragma unroll
    for (int n = 0; n < 2; ++n)
#pragma unroll
      for (int ks = 0; ks < 2; ++ks)
        b[n][ks] = *(const bf16x8*)(s + bOff[nb + n][ks]);
  };
  auto Q = [&](int mb, int nb, bf16x8 (&b)[2][2]) {
#pragma unroll
    for (int m = 0; m < 4; ++m)
#pragma unroll
      for (int n = 0; n < 2; ++n)
#pragma unroll
        for (int ks = 0; ks < 2; ++ks)
          acc[mb + m][nb + n] = __builtin_amdgcn_mfma_f32_16x16x32_bf16(
              aF[m][ks], b[n][ks], acc[mb + m][nb + n], 0, 0, 0);
  };

  for (int it = 0; it < 16; ++it) {
    int j = 2 * it;
    const char* s0 = smem;            // even kt buffer
    const char* s1 = smem + 65536;    // odd kt buffer

    // ======== K-tile j (buf0), phases 1-4 ========
    // P1: Q0 (m0-3 x n0-1), 12 ds_reads, stage kt j+1 . A1
    LDA(s0, 0); LDB(s0, bN0, 0);
    stA(j + 1, 1);
    BAR; PRIO1; Q(0, 0, bN0); PRIO0; BAR;
    // P2: Q1 (m0-3 x n2-3), 4 ds_reads
    LDB(s0, bN2, 2);
    BAR; PRIO1; Q(0, 2, bN2); PRIO0; BAR;
    // P3: Q2 (m4-7 x n0-1), 8 ds_reads, stage kt j+2 . B0
    LDA(s0, 4);
    stB(j + 2, 0);
    BAR; PRIO1; Q(4, 0, bN0); PRIO0; BAR;
    // P4: Q3 (m4-7 x n2-3), 0 ds_reads, stage kt j+2 . A0,B1 ; vmcnt(6)
    stA(j + 2, 0); stB(j + 2, 1);
    BAR; PRIO1; Q(4, 2, bN2); PRIO0;
    VM6;
    BAR;

    // ======== K-tile j+1 (buf1), phases 5-8 ========
    // P5: stage kt j+2 . A1
    LDA(s1, 0); LDB(s1, bN0, 0);
    stA(j + 2, 1);
    BAR; PRIO1; Q(0, 0, bN0); PRIO0; BAR;
    // P6
    LDB(s1, bN2, 2);
    BAR; PRIO1; Q(0, 2, bN2); PRIO0; BAR;
    // P7: stage kt j+3 . B0
    LDA(s1, 4);
    stB(j + 3, 0);
    BAR; PRIO1; Q(4, 0, bN0); PRIO0; BAR;
    // P8: stage kt j+3 . A0,B1 ; vmcnt(6)
    stA(j + 3, 0); stB(j + 3, 1);
    BAR; PRIO1; Q(4, 2, bN2); PRIO0;
    VM6;
    BAR;
  }
  asm volatile("s_waitcnt vmcnt(0)" ::: "memory");

  // ---- fused LSTM epilogue: nf 0..3 = gates i,f,g,o at the same column ----
  int col = (cb * 4 + wc) * 16 + l15;
  float Bi = b_i[col], Bf = b_f[col], Bg = b_g[col], Bo = b_o[col];
  const size_t HN = (size_t)8192 * 1024;
#pragma unroll
  for (int mf = 0; mf < 8; ++mf) {
    int row0 = rbB * 256 + wm * 128 + mf * 16 + lq * 4;
#pragma unroll
    for (int r = 0; r < 4; ++r) {
      int row = row0 + r;
      float xi = acc[mf][0][r] + Bi, xf = acc[mf][1][r] + Bf;
      float xg = acc[mf][2][r] + Bg, xo = acc[mf][3][r] + Bo;
      float iv = 1.f / (1.f + __expf(-xi));
      float fv = 1.f / (1.f + __expf(-xf));
      float gv = 1.f - 2.f / (__expf(2.f * xg) + 1.f);
      float ov = 1.f / (1.f + __expf(-xo));
      float cv = c_in[(size_t)row * 1024 + col];
      float cn = fv * cv + iv * gv;
      float tc = 1.f - 2.f / (__expf(2.f * cn) + 1.f);
      out[(size_t)row * 1024 + col]      = ov * tc;  // h_new
      out[HN + (size_t)row * 1024 + col] = cn;       // c_new
    }
  }
#undef BAR
#undef PRIO1
#undef PRIO0
#undef VM6
}

extern "C" void kernel_launch(void* const* d_in, const int* in_sizes, int n_in,
                              void* d_out, int out_size, void* d_ws, size_t ws_size,
                              hipStream_t stream) {
  const float* x  = (const float*)d_in[0];
  const float* h  = (const float*)d_in[1];
  const float* c  = (const float*)d_in[2];
  const float* Wi = (const float*)d_in[3];
  const float* Wf = (const float*)d_in[4];
  const float* Wg = (const float*)d_in[5];
  const float* Wo = (const float*)d_in[6];
  const float* bi = (const float*)d_in[7];
  const float* bf = (const float*)d_in[8];
  const float* bg = (const float*)d_in[9];
  const float* bo = (const float*)d_in[10];

  char* Ap = (char*)d_ws;                               // 32 MB
  char* Wp = Ap + (size_t)8192 * 2048 * 2;              // 16 MB
  float* out = (float*)d_out;

  hipLaunchKernelGGL(pack_a, dim3(8192), dim3(256), 0, stream, x, h, Ap);
  hipLaunchKernelGGL(pack_w, dim3(32, 16, 4), dim3(256), 0, stream, Wi, Wf, Wg, Wo, Wp);
  hipLaunchKernelGGL(lstm_gemm, dim3(512), dim3(512), 0, stream,
                     Ap, Wp, c, bi, bf, bg, bo, out);
}